// Round 8
// baseline (248.786 us; speedup 1.0000x reference)
//
#include <hip/hip_runtime.h>
#include <hip/hip_bf16.h>

namespace {
constexpr int Bn = 128, Cn = 2048, Nn = 196, Sn = 312, Ln = 300, Mn = 1024;
constexpr int Sp = 320, Lp = 320, PR = 192;

// f32-unit workspace offsets (all multiples of 4 f32 = 16 B)
constexpr size_t OFF_F16   = 0;                                  // fT fp16 [Bn*Nn][Cn]
constexpr size_t OFF_POOLX = OFF_F16   + (size_t)Bn*Nn*Cn/2;     // fp16 [PR][Cn] (rows 0-127 pool, 128 bo+bvo)
constexpr size_t OFF_HC    = OFF_POOLX + (size_t)PR*Cn/2;        // fp16 [Cn][Lp]  Hc[c][l] = sum_m Wk[c,m]Wq[l,m]
constexpr size_t OFF_WVM   = OFF_HC    + (size_t)Cn*Lp/2;        // fp16 [Sp][Mn]  WV = V @ Wo^T
constexpr size_t OFF_V16   = OFF_WVM   + (size_t)Sp*Mn/2;        // fp16 [Sp][Cn]
constexpr size_t OFF_WV16  = OFF_V16   + (size_t)Sp*Cn/2;        // fp16 [Cn][Mn]
constexpr size_t OFF_W2V   = OFF_WV16  + (size_t)Cn*Mn/2;        // fp16 [Sp][Lp]
constexpr size_t OFF_BQK   = OFF_W2V   + (size_t)Sp*Lp/2;        // f32 [Cn]  bq @ Wk^T
constexpr size_t OFF_QK    = OFF_BQK   + Cn;                     // fp16 [Sp][Cn]
constexpr size_t OFF_WWT   = OFF_QK    + (size_t)Sp*Cn/2;        // fp16 [Sp][Cn]
constexpr size_t OFF_PVF   = OFF_WWT   + (size_t)Sp*Cn/2;        // f32 [PR][Sp] (row b = pool.V, row 128 = cst)
}

typedef __attribute__((ext_vector_type(8))) short u16x8;
typedef __attribute__((ext_vector_type(8))) _Float16 f16x8;
typedef __attribute__((ext_vector_type(4))) _Float16 f16x4;
typedef __attribute__((ext_vector_type(4))) float f32x4;

__device__ __forceinline__ f16x8 as_h(u16x8 v) { return __builtin_bit_cast(f16x8, v); }

__device__ __forceinline__ void gload16(void* lds, const void* g) {
    __builtin_amdgcn_global_load_lds(
        (const __attribute__((address_space(1))) void*)g,
        (__attribute__((address_space(3))) void*)lds, 16, 0, 0);
}

// Stage a [rows x 32] fp16 tile (nslots = rows*4 16B-slots). LDS linear; XOR
// swizzle (chunk ^= (row>>1)&3) applied on the SOURCE address so the matching
// swizzled frag_ld reads are conflict-free.
__device__ __forceinline__ void stage_rows(ushort* lds, const ushort* src,
                                           size_t row0, int k0, int ld,
                                           int tid, int nslots) {
    int base = 0;
    for (; base + 256 <= nslots; base += 256) {
        const int slot = base + tid;
        const int r = slot >> 2, q = (slot & 3) ^ ((r >> 1) & 3);
        gload16(lds + (size_t)(base + (tid & 192)) * 8,
                src + (row0 + r) * (size_t)ld + k0 + q * 8);
    }
    const int rem = nslots - base;
    if (rem && tid < rem) {
        const int slot = base + tid;
        const int r = slot >> 2, q = (slot & 3) ^ ((r >> 1) & 3);
        gload16(lds + (size_t)base * 8,
                src + (row0 + r) * (size_t)ld + k0 + q * 8);
    }
}

// read one 16x32 fragment (lane l: row = fr*16 + (l&15), k-chunk = l>>4)
__device__ __forceinline__ u16x8 frag_ld(const ushort* tile, int fr, int lane) {
    const int rl = lane & 15;
    const int q  = (lane >> 4) ^ ((rl >> 1) & 3);
    return *(const u16x8*)(tile + ((fr * 16 + rl) * 32 + q * 8));
}

// ---- mini GEMM, fp16 inputs via global_load_lds: out[r][c] = sum_k A[r,k]B[c,k] ----
__device__ __forceinline__ void mini16(
        const ushort* __restrict__ A, int lda, const ushort* __restrict__ B, int ldb,
        int r0, int c0, int K, const float* __restrict__ bias,
        _Float16* __restrict__ outh, float* __restrict__ outf, int ldo,
        ushort* sA, ushort* sB, int tid) {
    const int lane = tid & 63, wid = tid >> 6;
    f32x4 acc[2][2];
    #pragma unroll
    for (int i = 0; i < 2; ++i)
        #pragma unroll
        for (int j = 0; j < 2; ++j) acc[i][j] = (f32x4)0.f;
    const int fa = (wid >> 1) * 2, fb = (wid & 1) * 2;
    for (int k0 = 0; k0 < K; k0 += 32) {
        stage_rows(sA, A, r0, k0, lda, tid, 256);
        stage_rows(sB, B, c0, k0, ldb, tid, 256);
        __syncthreads();
        f16x8 a0 = as_h(frag_ld(sA, fa, lane)), a1 = as_h(frag_ld(sA, fa + 1, lane));
        f16x8 b0 = as_h(frag_ld(sB, fb, lane)), b1 = as_h(frag_ld(sB, fb + 1, lane));
        acc[0][0] = __builtin_amdgcn_mfma_f32_16x16x32_f16(a0, b0, acc[0][0], 0, 0, 0);
        acc[0][1] = __builtin_amdgcn_mfma_f32_16x16x32_f16(a0, b1, acc[0][1], 0, 0, 0);
        acc[1][0] = __builtin_amdgcn_mfma_f32_16x16x32_f16(a1, b0, acc[1][0], 0, 0, 0);
        acc[1][1] = __builtin_amdgcn_mfma_f32_16x16x32_f16(a1, b1, acc[1][1], 0, 0, 0);
        __syncthreads();
    }
    #pragma unroll
    for (int i = 0; i < 2; ++i)
        #pragma unroll
        for (int j = 0; j < 2; ++j)
            #pragma unroll
            for (int rr = 0; rr < 4; ++rr) {
                const size_t row = r0 + (wid >> 1) * 32 + i * 16 + (lane >> 4) * 4 + rr;
                const int col = c0 + (wid & 1) * 32 + j * 16 + (lane & 15);
                const float v = acc[i][j][rr] + (bias ? bias[col] : 0.f);
                if (outh) outh[row * ldo + col] = (_Float16)v;
                else      outf[row * ldo + col] = v;
            }
}

// ---- mini GEMM, f32 inputs with inline fp16 convert (reg-staged, row guards) ----
__device__ __forceinline__ void mini_f32in(
        const float* __restrict__ A, int lda, int RA,
        const float* __restrict__ B, int ldb, int RB,
        int r0, int c0, int K, _Float16* __restrict__ out, int ldo,
        ushort* sA, ushort* sB, int tid) {
    const int lane = tid & 63, wid = tid >> 6;
    f32x4 acc[2][2];
    #pragma unroll
    for (int i = 0; i < 2; ++i)
        #pragma unroll
        for (int j = 0; j < 2; ++j) acc[i][j] = (f32x4)0.f;
    const int fa = (wid >> 1) * 2, fb = (wid & 1) * 2;
    for (int k0 = 0; k0 < K; k0 += 32) {
        #pragma unroll
        for (int p = 0; p < 2; ++p) {
            const int e = tid + p * 256;          // 512 8B-slots over [64][32]
            const int r = e >> 3, k4 = (e & 7) * 4;
            const int ad = r * 32 + (((k4 >> 3) ^ ((r >> 1) & 3)) << 3) + (k4 & 7);
            float4 va = (r0 + r < RA) ? *(const float4*)&A[(size_t)(r0 + r) * lda + k0 + k4]
                                      : make_float4(0.f, 0.f, 0.f, 0.f);
            f16x4 ha;
            ha[0] = (_Float16)va.x; ha[1] = (_Float16)va.y;
            ha[2] = (_Float16)va.z; ha[3] = (_Float16)va.w;
            *(f16x4*)&sA[ad] = ha;
            float4 vb = (c0 + r < RB) ? *(const float4*)&B[(size_t)(c0 + r) * ldb + k0 + k4]
                                      : make_float4(0.f, 0.f, 0.f, 0.f);
            f16x4 hb;
            hb[0] = (_Float16)vb.x; hb[1] = (_Float16)vb.y;
            hb[2] = (_Float16)vb.z; hb[3] = (_Float16)vb.w;
            *(f16x4*)&sB[ad] = hb;
        }
        __syncthreads();
        f16x8 a0 = as_h(frag_ld(sA, fa, lane)), a1 = as_h(frag_ld(sA, fa + 1, lane));
        f16x8 b0 = as_h(frag_ld(sB, fb, lane)), b1 = as_h(frag_ld(sB, fb + 1, lane));
        acc[0][0] = __builtin_amdgcn_mfma_f32_16x16x32_f16(a0, b0, acc[0][0], 0, 0, 0);
        acc[0][1] = __builtin_amdgcn_mfma_f32_16x16x32_f16(a0, b1, acc[0][1], 0, 0, 0);
        acc[1][0] = __builtin_amdgcn_mfma_f32_16x16x32_f16(a1, b0, acc[1][0], 0, 0, 0);
        acc[1][1] = __builtin_amdgcn_mfma_f32_16x16x32_f16(a1, b1, acc[1][1], 0, 0, 0);
        __syncthreads();
    }
    #pragma unroll
    for (int i = 0; i < 2; ++i)
        #pragma unroll
        for (int j = 0; j < 2; ++j)
            #pragma unroll
            for (int rr = 0; rr < 4; ++rr) {
                const size_t row = r0 + (wid >> 1) * 32 + i * 16 + (lane >> 4) * 4 + rr;
                const int col = c0 + (wid & 1) * 32 + j * 16 + (lane & 15);
                out[row * ldo + col] = (_Float16)acc[i][j][rr];
            }
}

// ================= STAGE A: everything reading only raw inputs =================
// grid: bvo(8) | bqk(512) | Hc(160) | WV(80) | cvtV(640) | cvtWv(2048) | cvtW2v(100) | prep(4096)
// Shared mem shrunk to 26.9 KB (prep tile now fp16) -> 6 blocks/CU (was 3).
__global__ __launch_bounds__(256) void k_stageA(
        const float* __restrict__ feat, const float* __restrict__ w2v,
        const float* __restrict__ Wq,  const float* __restrict__ bq,
        const float* __restrict__ Wk,  const float* __restrict__ Wv,
        const float* __restrict__ bv,  const float* __restrict__ Wo,
        const float* __restrict__ bo,  const float* __restrict__ Vf,
        _Float16* __restrict__ f16, _Float16* __restrict__ poolx,
        _Float16* __restrict__ hc, _Float16* __restrict__ wvm,
        _Float16* __restrict__ v16, _Float16* __restrict__ wv16,
        _Float16* __restrict__ w2v16, float* __restrict__ bqk) {
    __shared__ __align__(16) char smem[26880];   // prep: 64*202*2 + 64*4*4 = 26880; mini: 8192
    const int tid = threadIdx.x;
    int i = blockIdx.x;
    if (i < 8) {
        // bvo: poolx row 128 = bo[c] + sum_m bv[m] Wo[m,c]
        const int c = i * 256 + tid;
        float acc = bo[c];
        #pragma unroll 8
        for (int m = 0; m < Mn; ++m) acc = fmaf(bv[m], Wo[(size_t)m * Cn + c], acc);
        poolx[(size_t)128 * Cn + c] = (_Float16)acc;
    } else if ((i -= 8) < 512) {
        // bqk[c] = sum_m bq[m] Wk[c,m]  (wave per c)
        const int lane = tid & 63;
        const int c = i * 4 + (tid >> 6);
        float acc = 0.f;
        for (int m = lane; m < Mn; m += 64) acc = fmaf(bq[m], Wk[(size_t)c * Mn + m], acc);
        #pragma unroll
        for (int mm = 32; mm; mm >>= 1) acc += __shfl_xor(acc, mm);
        if (lane == 0) bqk[c] = acc;
    } else if ((i -= 512) < 160) {
        // Hc[c][l] = sum_m Wk[c,m] Wq[l,m]   [Cn][Lp]
        ushort* sA = (ushort*)smem;
        mini_f32in(Wk, Mn, 1 << 30, Wq, Mn, Ln,
                   (i / 5) * 64, (i % 5) * 64, Mn, hc, Lp, sA, sA + 2048, tid);
    } else if ((i -= 160) < 80) {
        // WV[s][m] = sum_c V[s,c] Wo[m,c]   [Sp][Mn]
        ushort* sA = (ushort*)smem;
        mini_f32in(Vf, Cn, Sn, Wo, Cn, 1 << 30,
                   (i / 16) * 64, (i % 16) * 64, Cn, wvm, Mn, sA, sA + 2048, tid);
    } else if ((i -= 80) < 640) {
        // cvt Vf -> v16 [Sp][Cn], pad rows 0
        const size_t idx = ((size_t)i * 256 + tid) * 4;
        const int r = (int)(idx >> 11);
        float4 v = (r < Sn) ? *(const float4*)&Vf[idx] : make_float4(0.f, 0.f, 0.f, 0.f);
        f16x4 h;
        h[0] = (_Float16)v.x; h[1] = (_Float16)v.y; h[2] = (_Float16)v.z; h[3] = (_Float16)v.w;
        *(f16x4*)&v16[idx] = h;
    } else if ((i -= 640) < 2048) {
        // cvt Wv -> wv16 [Cn][Mn]  (2048 blocks x 1024 elem = Cn*Mn)
        const size_t idx = ((size_t)i * 256 + tid) * 4;
        const float4 v = *(const float4*)&Wv[idx];
        f16x4 h;
        h[0] = (_Float16)v.x; h[1] = (_Float16)v.y; h[2] = (_Float16)v.z; h[3] = (_Float16)v.w;
        *(f16x4*)&wv16[idx] = h;
    } else if ((i -= 2048) < 100) {
        // cvt w2v [Sn][Ln] -> w2v16 [Sp][Lp], zero-padded
        const int e0 = (i * 256 + tid) * 4;
        #pragma unroll
        for (int k = 0; k < 4; ++k) {
            const int e = e0 + k;
            const int r = e / Lp, cl = e - r * Lp;
            w2v16[e] = (r < Sn && cl < Ln) ? (_Float16)w2v[(size_t)r * Ln + cl] : (_Float16)0.f;
        }
    } else {
        // prep_feat: feat[b][c][n] -> f16[(b*196+n)][c] + poolx rows 0-127
        // fp16 LDS tile [64][202] (stride 202: bank stride 101 ~ gcd 1 -> low conflicts)
        i -= 100;
        ushort (*t16)[202] = (ushort(*)[202])smem;
        float (*pp)[4]     = (float(*)[4])(smem + 64 * 202 * 2);
        const int b = i >> 5, c0 = (i & 31) * 64;
        for (int u = tid; u < 64 * 49; u += 256) {
            const int r = u / 49, nq = u - r * 49;
            const float4 v = *(const float4*)&feat[((size_t)b * Cn + c0 + r) * Nn + nq * 4];
            f16x4 h;
            h[0] = (_Float16)v.x; h[1] = (_Float16)v.y;
            h[2] = (_Float16)v.z; h[3] = (_Float16)v.w;
            *(uint*)&t16[r][nq * 4]     = ((uint*)&h)[0];
            *(uint*)&t16[r][nq * 4 + 2] = ((uint*)&h)[1];
        }
        __syncthreads();
        {   // pool partials from f16 tile (err ~1e-5, negligible)
            const int c = tid >> 2, q = tid & 3;
            float s = 0.f;
            const int n0 = q * 49;
            #pragma unroll
            for (int n = 0; n < 49; ++n)
                s += (float)*(const _Float16*)&t16[c][n0 + n];
            pp[c][q] = s;
        }
        for (int u = tid; u < Nn * 16; u += 256) {
            const int n = u >> 4, cq = (u & 15) * 4;
            ushort4 o;
            o.x = t16[cq + 0][n]; o.y = t16[cq + 1][n];
            o.z = t16[cq + 2][n]; o.w = t16[cq + 3][n];
            *(ushort4*)((ushort*)f16 + ((size_t)b * Nn + n) * Cn + c0 + cq) = o;
        }
        __syncthreads();
        if (tid < 64)
            poolx[(size_t)b * Cn + c0 + tid] =
                (_Float16)((pp[tid][0] + pp[tid][1] + pp[tid][2] + pp[tid][3]) * (1.0f / Nn));
    }
}

// ================= STAGE B: qk | WWt | pv+cst =================
__global__ __launch_bounds__(256) void k_stageB(
        const ushort* __restrict__ w2v16, const ushort* __restrict__ hc,
        const float* __restrict__ bqk, const ushort* __restrict__ wvm,
        const ushort* __restrict__ wv16, const ushort* __restrict__ poolx,
        const ushort* __restrict__ v16,
        _Float16* __restrict__ qk16, _Float16* __restrict__ wwt16,
        float* __restrict__ pvf) {
    __shared__ __align__(16) ushort sA[2048], sB[2048];
    const int tid = threadIdx.x;
    int i = blockIdx.x;
    if (i < 160) {
        // qk[s][c] = sum_l w2v[s,l] Hc[c,l] + bqk[c]
        mini16(w2v16, Lp, hc, Lp, (i / 32) * 64, (i % 32) * 64, Lp,
               bqk, qk16, nullptr, Cn, sA, sB, tid);
    } else if ((i -= 160) < 160) {
        // WWt[s][c] = sum_m WV[s,m] Wv[c,m]
        mini16(wvm, Mn, wv16, Mn, (i / 32) * 64, (i % 32) * 64, Mn,
               nullptr, wwt16, nullptr, Cn, sA, sB, tid);
    } else {
        // pvf[row][s] = sum_c poolx[row,c] V[s,c]  (row 128 = cst)
        i -= 160;
        mini16(poolx, Cn, v16, Cn, (i / 5) * 64, (i % 5) * 64, Cn,
               nullptr, nullptr, pvf, Sp, sA, sB, tid);
    }
}

// ====== fused attention: double-buffered, __syncthreads-safe prefetch ======
__global__ __launch_bounds__(256) void k_attn(
        const _Float16* __restrict__ f16, const _Float16* __restrict__ qk16,
        const _Float16* __restrict__ ww16, const float* __restrict__ pvf,
        float* __restrict__ out) {
    __shared__ __align__(16) ushort smem[2][10752];   // per buf: F 6656 | Q 2048 | W 2048
    const int tid = threadIdx.x, lane = tid & 63, wid = tid >> 6;
    const int id = blockIdx.x;
    const int xcd = id & 7, slot = id >> 3;
    const int b  = xcd * 16 + slot / 5;   // 5 sibling s-tiles -> same XCD
    const int s0 = (slot % 5) * 64;
    const size_t frow0 = (size_t)b * Nn;

    f32x4 sc[13], vw[13];
    #pragma unroll
    for (int j = 0; j < 13; ++j) { sc[j] = (f32x4)0.f; vw[j] = (f32x4)0.f; }

    auto stage3 = [&](int p, int k0) {
        ushort* s = smem[p];
        stage_rows(s,        (const ushort*)f16,  frow0, k0, Cn, tid, 832);
        stage_rows(s + 6656, (const ushort*)qk16, s0,    k0, Cn, tid, 256);
        stage_rows(s + 8704, (const ushort*)ww16, s0,    k0, Cn, tid, 256);
    };

    constexpr int NIT = Cn / 32;
    stage3(0, 0);
    for (int t = 0; t < NIT; ++t) {
        const int cur = t & 1;
        __syncthreads();                       // full drain: tile-t data ready
        if (t + 1 < NIT) stage3(cur ^ 1, (t + 1) * 32);   // prefetch under MFMA
        const ushort* sF = smem[cur];
        const f16x8 qf = as_h(frag_ld(sF + 6656, wid, lane));
        const f16x8 wf = as_h(frag_ld(sF + 8704, wid, lane));
        #pragma unroll
        for (int j = 0; j < 13; ++j) {
            const f16x8 ff = as_h(frag_ld(sF, j, lane));
            sc[j] = __builtin_amdgcn_mfma_f32_16x16x32_f16(qf, ff, sc[j], 0, 0, 0);
            vw[j] = __builtin_amdgcn_mfma_f32_16x16x32_f16(wf, ff, vw[j], 0, 0, 0);
        }
    }

    // per-row softmax over n (cols on 16-lane groups) + contraction
    const int g = lane & 15;
    #pragma unroll
    for (int rr = 0; rr < 4; ++rr) {
        float mx = -1e30f;
        #pragma unroll
        for (int j = 0; j < 13; ++j)
            if (j < 12 || g < 4) mx = fmaxf(mx, sc[j][rr]);
        #pragma unroll
        for (int mm = 1; mm < 16; mm <<= 1) mx = fmaxf(mx, __shfl_xor(mx, mm));
        float den = 0.f, num = 0.f;
        #pragma unroll
        for (int j = 0; j < 13; ++j)
            if (j < 12 || g < 4) {
                const float e = __expf(sc[j][rr] - mx);
                den += e;
                num = fmaf(e, vw[j][rr], num);
            }
        #pragma unroll
        for (int mm = 1; mm < 16; mm <<= 1) {
            den += __shfl_xor(den, mm);
            num += __shfl_xor(num, mm);
        }
        if (g == 0) {
            const int s = s0 + wid * 16 + (lane >> 4) * 4 + rr;
            if (s < Sn)
                out[(size_t)b * Sn + s] =
                    pvf[(size_t)b * Sp + s] + pvf[(size_t)128 * Sp + s] + num / den;
        }
    }
}

extern "C" void kernel_launch(void* const* d_in, const int* in_sizes, int n_in,
                              void* d_out, int out_size, void* d_ws, size_t ws_size,
                              hipStream_t stream) {
    (void)in_sizes; (void)n_in; (void)ws_size; (void)out_size;
    const float* feat = (const float*)d_in[0];
    const float* w2v  = (const float*)d_in[1];
    const float* Wq   = (const float*)d_in[2];
    const float* bq   = (const float*)d_in[3];
    const float* Wk   = (const float*)d_in[4];
    const float* Wv   = (const float*)d_in[6];
    const float* bv   = (const float*)d_in[7];
    const float* Wo   = (const float*)d_in[8];
    const float* bo   = (const float*)d_in[9];
    const float* Vf   = (const float*)d_in[10];
    float* out = (float*)d_out;
    float* ws  = (float*)d_ws;

    _Float16* f16   = (_Float16*)(ws + OFF_F16);
    _Float16* poolx = (_Float16*)(ws + OFF_POOLX);
    _Float16* hc    = (_Float16*)(ws + OFF_HC);
    _Float16* wvm   = (_Float16*)(ws + OFF_WVM);
    _Float16* v16   = (_Float16*)(ws + OFF_V16);
    _Float16* wv16  = (_Float16*)(ws + OFF_WV16);
    _Float16* w2v16 = (_Float16*)(ws + OFF_W2V);
    float*    bqk   = ws + OFF_BQK;
    _Float16* qk16  = (_Float16*)(ws + OFF_QK);
    _Float16* wwt16 = (_Float16*)(ws + OFF_WWT);
    float*    pvf   = ws + OFF_PVF;

    k_stageA<<<dim3(8 + 512 + 160 + 80 + 640 + 2048 + 100 + 4096), 256, 0, stream>>>(
        feat, w2v, Wq, bq, Wk, Wv, bv, Wo, bo, Vf,
        f16, poolx, hc, wvm, v16, wv16, w2v16, bqk);
    k_stageB<<<dim3(160 + 160 + 15), 256, 0, stream>>>(
        (const ushort*)w2v16, (const ushort*)hc, bqk, (const ushort*)wvm,
        (const ushort*)wv16, (const ushort*)poolx, (const ushort*)v16,
        qk16, wwt16, pvf);
    k_attn<<<dim3(640), 256, 0, stream>>>(f16, qk16, wwt16, pvf, out);
}